// Round 1
// baseline (758.052 us; speedup 1.0000x reference)
//
#include <hip/hip_runtime.h>

// Problem constants
#define BATCH   16
#define CDIM    256
#define HDIM    32
#define WDIM    32
#define NPTS    16384      // B*H*W
#define KCODES  8192
#define NELEM   4194304    // B*C*H*W
// z strides (float32 [B,C,H,W]): b: 262144, c: 1024, hw: 1

// ---------------------------------------------------------------------------
// Kernel 0: zz[n] = sum_c z[n,c]^2   (fp32; exact order irrelevant, ulp-level
// differences shift all quantized distances uniformly -> argmin invariant)
// ---------------------------------------------------------------------------
__global__ __launch_bounds__(256) void k_zz(const float* __restrict__ z,
                                            float* __restrict__ zz) {
    const int n0 = blockIdx.x * 64;          // 256 blocks x 64 points
    const int b = n0 >> 10, hw0 = n0 & 1023;
    const int p = threadIdx.x & 63, g = threadIdx.x >> 6;   // 64 pts x 4 c-groups
    const float* zb = z + b * 262144 + hw0 + p;
    float s = 0.f;
    #pragma unroll 4
    for (int c = g * 64; c < g * 64 + 64; ++c) {
        float v = zb[c * 1024];
        s = fmaf(v, v, s);
    }
    __shared__ float red[4][64];
    red[g][p] = s;
    __syncthreads();
    if (g == 0)
        zz[n0 + p] = (red[0][p] + red[1][p]) + (red[2][p] + red[3][p]);
}

// ---------------------------------------------------------------------------
// Kernel 1: distances + partial argmin.
// Block tile: 128 points x 128 codes, 256 threads (16x16), 8x8 regs/thread.
// d = fl32(zz - 2*dot) exactly as numpy computes it (2*dot is exact scaling,
// so fmaf(-2, dot, zz) == fl(zz - fl(2*dot))).  First-index tie-break via
// packed u64 (dist_bits<<32 | k) min.
// ---------------------------------------------------------------------------
__global__ __launch_bounds__(256) void k_argmin(const float* __restrict__ z,
                                                const float* __restrict__ emb,
                                                const float* __restrict__ zz,
                                                unsigned long long* __restrict__ best) {
    const int bid = blockIdx.x;
    const int bm = bid >> 6;            // 0..127  (point tile)
    const int bk = bid & 63;            // 0..63   (code tile)
    const int m0 = bm * 128;
    const int k0 = bk * 128;
    const int b = m0 >> 10, hw0 = m0 & 1023;
    const float* zbase = z + b * 262144 + hw0;   // + c*1024 + m

    const int t  = threadIdx.x;
    const int tx = t & 15, ty = t >> 4;

    __shared__ __align__(16) float zs[16][132];  // [c][m], pad->conflict-free
    __shared__ __align__(16) float es[16][132];  // [c][k]

    float acc[8][8];
    #pragma unroll
    for (int r = 0; r < 8; ++r)
        #pragma unroll
        for (int s = 0; s < 8; ++s) acc[r][s] = 0.f;

    // staging assignments
    const int zc = t >> 4;              // 0..15 channel
    const int zm = (t & 15) * 8;        // 0..120 point
    const int ek = t >> 1;              // 0..127 code row
    const int ec = (t & 1) * 8;         // 0 or 8 channel base

    for (int cc = 0; cc < 256; cc += 16) {
        const float4* zg = reinterpret_cast<const float4*>(zbase + (cc + zc) * 1024 + zm);
        float4 a0 = zg[0], a1 = zg[1];
        const float4* eg = reinterpret_cast<const float4*>(emb + (k0 + ek) * 256 + cc + ec);
        float4 e0 = eg[0], e1 = eg[1];
        __syncthreads();   // previous chunk fully consumed
        *reinterpret_cast<float4*>(&zs[zc][zm])     = a0;
        *reinterpret_cast<float4*>(&zs[zc][zm + 4]) = a1;
        es[ec + 0][ek] = e0.x; es[ec + 1][ek] = e0.y;
        es[ec + 2][ek] = e0.z; es[ec + 3][ek] = e0.w;
        es[ec + 4][ek] = e1.x; es[ec + 5][ek] = e1.y;
        es[ec + 6][ek] = e1.z; es[ec + 7][ek] = e1.w;
        __syncthreads();
        #pragma unroll
        for (int c = 0; c < 16; ++c) {
            float a[8], bb[8];
            *reinterpret_cast<float4*>(&a[0])  = *reinterpret_cast<const float4*>(&zs[c][ty * 4]);
            *reinterpret_cast<float4*>(&a[4])  = *reinterpret_cast<const float4*>(&zs[c][64 + ty * 4]);
            *reinterpret_cast<float4*>(&bb[0]) = *reinterpret_cast<const float4*>(&es[c][tx * 4]);
            *reinterpret_cast<float4*>(&bb[4]) = *reinterpret_cast<const float4*>(&es[c][64 + tx * 4]);
            #pragma unroll
            for (int r = 0; r < 8; ++r)
                #pragma unroll
                for (int s = 0; s < 8; ++s)
                    acc[r][s] = fmaf(a[r], bb[s], acc[r][s]);
        }
    }

    // epilogue: d = fl(zz - 2*dot), pack, reduce over this block's 128 codes
    #pragma unroll
    for (int r = 0; r < 8; ++r) {
        const int p = ty * 4 + (r & 3) + ((r >> 2) << 6);   // local point 0..127
        const float zzv = zz[m0 + p];
        unsigned long long key = ~0ull;
        #pragma unroll
        for (int s = 0; s < 8; ++s) {
            const int k = k0 + tx * 4 + (s & 3) + ((s >> 2) << 6);
            float d = fmaf(-2.f, acc[r][s], zzv);
            unsigned long long kk =
                ((unsigned long long)__float_as_uint(d) << 32) | (unsigned)k;
            key = kk < key ? kk : key;
        }
        #pragma unroll
        for (int m = 1; m < 16; m <<= 1) {
            unsigned long long o = __shfl_xor(key, m);
            key = o < key ? o : key;
        }
        if (tx == 0) atomicMin(&best[m0 + p], key);
    }
}

// ---------------------------------------------------------------------------
// Kernel 2: gather + straight-through output + loss partial sums + idx output
// out0 = fl(zp + fl(e - zp))  (replicates reference rounding exactly)
// ---------------------------------------------------------------------------
__global__ __launch_bounds__(256) void k_out(const float* __restrict__ z,
                                             const float* __restrict__ emb,
                                             const unsigned long long* __restrict__ best,
                                             float* __restrict__ out0,
                                             float* __restrict__ out2,
                                             double* __restrict__ loss) {
    const int n0 = blockIdx.x * 64;          // 256 blocks x 64 points
    const int b = n0 >> 10, hw0 = n0 & 1023;
    const int p = threadIdx.x & 63, cg = threadIdx.x >> 6;
    const int n = n0 + p;
    const int idx = (int)(unsigned)(best[n] & 0xffffffffull);
    if (threadIdx.x < 64)
        out2[n0 + threadIdx.x] =
            (float)(int)(unsigned)(best[n0 + threadIdx.x] & 0xffffffffull);

    const float* zb = z + b * 262144 + hw0 + p;
    float*       ob = out0 + b * 262144 + hw0 + p;
    const float* eb = emb + idx * 256;
    double ls = 0.0;
    #pragma unroll 4
    for (int c = cg * 64; c < cg * 64 + 64; ++c) {
        float zp = zb[c * 1024];
        float e  = eb[c];
        float diff = e - zp;             // fl(z_q - zp)
        ob[c * 1024] = zp + diff;        // fl(zp + fl(z_q - zp))
        float l = zp - e;
        ls += (double)l * (double)l;
    }
    __shared__ double red[256];
    red[threadIdx.x] = ls;
    __syncthreads();
    for (int s = 128; s > 0; s >>= 1) {
        if (threadIdx.x < s) red[threadIdx.x] += red[threadIdx.x + s];
        __syncthreads();
    }
    if (threadIdx.x == 0) atomicAdd(loss, red[0]);
}

__global__ void k_loss(const double* __restrict__ loss, float* __restrict__ out1) {
    float m = (float)(*loss / (double)NELEM);
    out1[0] = 0.25f * m + m;   // BETA*mean + mean, matching fl(0.25m)+m
}

// ---------------------------------------------------------------------------
extern "C" void kernel_launch(void* const* d_in, const int* in_sizes, int n_in,
                              void* d_out, int out_size, void* d_ws, size_t ws_size,
                              hipStream_t stream) {
    const float* z   = (const float*)d_in[0];
    const float* emb = (const float*)d_in[1];
    float* out  = (float*)d_out;
    float* out0 = out;                 // 4194304 floats [B,C,H,W]
    float* out1 = out + NELEM;         // 1 float (vq_loss)
    float* out2 = out + NELEM + 1;     // 16384 floats (idx as float)

    unsigned long long* best = (unsigned long long*)d_ws;          // 128 KB
    float*  zz   = (float*)((char*)d_ws + NPTS * 8);               // 64 KB
    double* loss = (double*)((char*)d_ws + NPTS * 8 + NPTS * 4);   // 8 B

    hipMemsetAsync(best, 0xFF, NPTS * 8, stream);
    hipMemsetAsync(loss, 0, 8, stream);
    k_zz<<<256, 256, 0, stream>>>(z, zz);
    k_argmin<<<8192, 256, 0, stream>>>(z, emb, zz, best);
    k_out<<<256, 256, 0, stream>>>(z, emb, best, out0, out2, loss);
    k_loss<<<1, 1, 0, stream>>>(loss, out1);
}

// Round 2
// 360.105 us; speedup vs baseline: 2.1051x; 2.1051x over previous
//
#include <hip/hip_runtime.h>

#define BATCH   16
#define CDIM    256
#define NPTS    16384      // B*H*W
#define KCODES  8192
#define NELEM   4194304    // B*C*H*W
#define ESCALE  4096.0f
#define MARGIN  0.5f       // in S = 4096*dot units

typedef _Float16 f16;
typedef _Float16 f16x8 __attribute__((ext_vector_type(8)));
typedef _Float16 f16x4 __attribute__((ext_vector_type(4)));
typedef float    f32x4 __attribute__((ext_vector_type(4)));

__device__ __forceinline__ void gload16(const void* g, void* l) {
    __builtin_amdgcn_global_load_lds(
        (const __attribute__((address_space(1))) unsigned int*)g,
        (__attribute__((address_space(3))) unsigned int*)l, 16, 0, 0);
}

// ---------------------------------------------------------------------------
// prep_z: zz[n] (same summation order as R1 — passed) + z16[n][c] f16 rows
// ---------------------------------------------------------------------------
__global__ __launch_bounds__(256) void k_prep_z(const float* __restrict__ z,
                                                f16* __restrict__ z16,
                                                float* __restrict__ zz) {
    __shared__ f16 tile[64][264];        // row stride 528 B (16B aligned)
    __shared__ float red[4][64];
    const int n0 = blockIdx.x * 64;
    const int b = n0 >> 10, hw0 = n0 & 1023;
    const int p = threadIdx.x & 63, g = threadIdx.x >> 6;
    const float* zb = z + b * 262144 + hw0 + p;
    float s = 0.f;
    for (int c = g * 64; c < g * 64 + 64; ++c) {
        float v = zb[c * 1024];
        s = fmaf(v, v, s);
        tile[p][c] = (f16)v;
    }
    red[g][p] = s;
    __syncthreads();
    if (g == 0) zz[n0 + p] = (red[0][p] + red[1][p]) + (red[2][p] + red[3][p]);
    const int r = threadIdx.x >> 2, q = threadIdx.x & 3;
    f16* dst = z16 + (size_t)(n0 + r) * 256 + q * 64;
    #pragma unroll
    for (int j = 0; j < 8; ++j)
        *(f16x8*)(dst + j * 8) = *(const f16x8*)(&tile[r][q * 64 + j * 8]);
}

// ---------------------------------------------------------------------------
// prep_e: e16[k][c] = f16(emb * 4096)
// ---------------------------------------------------------------------------
__global__ __launch_bounds__(256) void k_prep_e(const float* __restrict__ emb,
                                                f16* __restrict__ e16) {
    const int i = (blockIdx.x * 256 + threadIdx.x) * 4;
    float4 v = *(const float4*)(emb + i);
    f16x4 o = {(f16)(v.x * ESCALE), (f16)(v.y * ESCALE),
               (f16)(v.z * ESCALE), (f16)(v.w * ESCALE)};
    *(f16x4*)(e16 + i) = o;
}

// ---------------------------------------------------------------------------
// gemm: S = z16 @ e16^T, 256x256 tile, 8 waves (2Mx4N), BK=64, dbuf LDS,
// global_load_lds w/ pre-swizzled source, XOR-swizzled ds_read_b128.
// Epilogue: per-point max over each 64-code group -> gmax16[n][128] (f16).
// ---------------------------------------------------------------------------
__device__ __forceinline__ void stage_tile(const f16* zg, const f16* eg,
                                           f16* Ab, f16* Bb, int t, int kt) {
    #pragma unroll
    for (int pp = 0; pp < 4; ++pp) {
        const int gi  = pp * 512 + t;          // granule 0..2047 (16B each)
        const int row = gi >> 3;               // 0..255
        const int kc  = (gi & 7) ^ (row & 7);  // inverse swizzle on source
        const size_t goff = (size_t)row * 256 + (size_t)kt * 64 + kc * 8;
        gload16(zg + goff, (char*)Ab + gi * 16);
        gload16(eg + goff, (char*)Bb + gi * 16);
    }
}

__global__ __launch_bounds__(512, 2) void k_gemm(const f16* __restrict__ z16,
                                                 const f16* __restrict__ e16,
                                                 f16* __restrict__ gmax16) {
    __shared__ f16 As[2][16384];   // [256 rows][64 k] *2 bufs = 64 KB
    __shared__ f16 Bs[2][16384];   // 64 KB
    const int bid = blockIdx.x;
    const int bm = bid >> 5, bn = bid & 31;
    const size_t m0 = (size_t)bm * 256, n0 = (size_t)bn * 256;
    const int t = threadIdx.x, lane = t & 63, w = t >> 6;
    const int wm = w >> 2, wn = w & 3;        // 2 x 4 waves, wave tile 128x64

    const f16* zg = z16 + m0 * 256;
    const f16* eg = e16 + n0 * 256;

    f32x4 acc[8][4] = {};

    stage_tile(zg, eg, As[0], Bs[0], t, 0);
    __syncthreads();

    for (int kt = 0; kt < 4; ++kt) {
        const int buf = kt & 1;
        if (kt < 3) stage_tile(zg, eg, As[buf ^ 1], Bs[buf ^ 1], t, kt + 1);
        const char* Ab = (const char*)As[buf];
        const char* Bb = (const char*)Bs[buf];
        #pragma unroll
        for (int kk = 0; kk < 2; ++kk) {
            f16x8 a[8], bf[4];
            const int kc = kk * 4 + (lane >> 4);
            #pragma unroll
            for (int mr = 0; mr < 8; ++mr) {
                const int row = wm * 128 + mr * 16 + (lane & 15);
                a[mr] = *(const f16x8*)(Ab + row * 128 + ((kc ^ (row & 7)) << 4));
            }
            #pragma unroll
            for (int nr = 0; nr < 4; ++nr) {
                const int row = wn * 64 + nr * 16 + (lane & 15);
                bf[nr] = *(const f16x8*)(Bb + row * 128 + ((kc ^ (row & 7)) << 4));
            }
            #pragma unroll
            for (int mr = 0; mr < 8; ++mr)
                #pragma unroll
                for (int nr = 0; nr < 4; ++nr)
                    acc[mr][nr] = __builtin_amdgcn_mfma_f32_16x16x32_f16(
                        a[mr], bf[nr], acc[mr][nr], 0, 0, 0);
        }
        __syncthreads();
    }

    // epilogue: per-point max over this wave's 64 codes (one group)
    const int g = bn * 4 + wn;
    #pragma unroll
    for (int mr = 0; mr < 8; ++mr) {
        #pragma unroll
        for (int q = 0; q < 4; ++q) {
            float v = acc[mr][0][q];
            v = fmaxf(v, acc[mr][1][q]);
            v = fmaxf(v, acc[mr][2][q]);
            v = fmaxf(v, acc[mr][3][q]);
            v = fmaxf(v, __shfl_xor(v, 1));
            v = fmaxf(v, __shfl_xor(v, 2));
            v = fmaxf(v, __shfl_xor(v, 4));
            v = fmaxf(v, __shfl_xor(v, 8));
            if ((lane & 15) == 0) {
                const int p = wm * 128 + mr * 16 + ((lane >> 4) << 2) + q;
                gmax16[(m0 + p) * 128 + g] = (f16)v;
            }
        }
    }
}

// ---------------------------------------------------------------------------
// rescore: per point (1 wave) — find global approx max, rescore all groups
// within MARGIN exactly in fp32 (same d formula as R1), first-index tiebreak.
// ---------------------------------------------------------------------------
__global__ __launch_bounds__(256) void k_rescore(const float* __restrict__ z,
                                                 const float* __restrict__ emb,
                                                 const float* __restrict__ zz,
                                                 const f16* __restrict__ gmax16,
                                                 unsigned long long* __restrict__ best) {
    const int n = blockIdx.x * 4 + (threadIdx.x >> 6);
    const int lane = threadIdx.x & 63;
    const int b = n >> 10, hw = n & 1023;
    const float* zb = z + b * 262144 + hw;
    const float z0 = zb[(lane * 4 + 0) * 1024];
    const float z1 = zb[(lane * 4 + 1) * 1024];
    const float z2 = zb[(lane * 4 + 2) * 1024];
    const float z3 = zb[(lane * 4 + 3) * 1024];

    union { unsigned u; f16 h[2]; } uu;
    uu.u = *(const unsigned*)((const char*)gmax16 + (size_t)n * 256 + lane * 4);
    const float g0 = (float)uu.h[0], g1 = (float)uu.h[1];  // groups 2l, 2l+1
    float m = fmaxf(g0, g1);
    #pragma unroll
    for (int s = 1; s < 64; s <<= 1) m = fmaxf(m, __shfl_xor(m, s));
    const float thr = m - MARGIN;
    unsigned long long f0 = __ballot(g0 >= thr);
    unsigned long long f1 = __ballot(g1 >= thr);
    const float zzv = zz[n];
    unsigned long long key = ~0ull;

    while (f0 | f1) {
        int g;
        if (f0) { const int l2 = __ffsll(f0) - 1; f0 &= f0 - 1; g = 2 * l2; }
        else    { const int l2 = __ffsll(f1) - 1; f1 &= f1 - 1; g = 2 * l2 + 1; }
        const float* eb = emb + (size_t)g * 64 * 256 + lane * 4;
        for (int j = 0; j < 64; ++j) {
            float4 e = *(const float4*)(eb + j * 256);
            float p = fmaf(z3, e.w, fmaf(z2, e.z, fmaf(z1, e.y, z0 * e.x)));
            #pragma unroll
            for (int s = 1; s < 64; s <<= 1) p += __shfl_xor(p, s);
            const float d = fmaf(-2.f, p, zzv);
            const unsigned long long kk =
                ((unsigned long long)__float_as_uint(d) << 32) | (unsigned)(g * 64 + j);
            if (kk < key) key = kk;
        }
    }
    if (lane == 0) best[n] = key;
}

// ---------------------------------------------------------------------------
// out + loss (unchanged from R1 — verified exact)
// ---------------------------------------------------------------------------
__global__ __launch_bounds__(256) void k_out(const float* __restrict__ z,
                                             const float* __restrict__ emb,
                                             const unsigned long long* __restrict__ best,
                                             float* __restrict__ out0,
                                             float* __restrict__ out2,
                                             double* __restrict__ loss) {
    const int n0 = blockIdx.x * 64;
    const int b = n0 >> 10, hw0 = n0 & 1023;
    const int p = threadIdx.x & 63, cg = threadIdx.x >> 6;
    const int n = n0 + p;
    const int idx = (int)(unsigned)(best[n] & 0xffffffffull);
    if (threadIdx.x < 64)
        out2[n0 + threadIdx.x] =
            (float)(int)(unsigned)(best[n0 + threadIdx.x] & 0xffffffffull);

    const float* zb = z + b * 262144 + hw0 + p;
    float*       ob = out0 + b * 262144 + hw0 + p;
    const float* eb = emb + idx * 256;
    double ls = 0.0;
    #pragma unroll 4
    for (int c = cg * 64; c < cg * 64 + 64; ++c) {
        float zp = zb[c * 1024];
        float e  = eb[c];
        float diff = e - zp;
        ob[c * 1024] = zp + diff;
        float l = zp - e;
        ls += (double)l * (double)l;
    }
    __shared__ double red[256];
    red[threadIdx.x] = ls;
    __syncthreads();
    for (int s = 128; s > 0; s >>= 1) {
        if (threadIdx.x < s) red[threadIdx.x] += red[threadIdx.x + s];
        __syncthreads();
    }
    if (threadIdx.x == 0) atomicAdd(loss, red[0]);
}

__global__ void k_loss(const double* __restrict__ loss, float* __restrict__ out1) {
    float m = (float)(*loss / (double)NELEM);
    out1[0] = 0.25f * m + m;
}

// ---------------------------------------------------------------------------
extern "C" void kernel_launch(void* const* d_in, const int* in_sizes, int n_in,
                              void* d_out, int out_size, void* d_ws, size_t ws_size,
                              hipStream_t stream) {
    const float* z   = (const float*)d_in[0];
    const float* emb = (const float*)d_in[1];
    float* out  = (float*)d_out;
    float* out0 = out;
    float* out1 = out + NELEM;
    float* out2 = out + NELEM + 1;

    // scratch inside d_out's out0 region (16 MB, fully rewritten by k_out):
    f16* z16    = (f16*)out0;                        // 8 MB
    f16* e16    = (f16*)((char*)out0 + 8388608);     // 4 MB
    f16* gmax16 = (f16*)((char*)out0 + 12582912);    // 4 MB (ends exactly at 16 MB)

    float* zzp = (float*)d_ws;                                    // 64 KB
    unsigned long long* best =
        (unsigned long long*)((char*)d_ws + 65536);               // 128 KB
    double* loss = (double*)((char*)d_ws + 65536 + 131072);       // 8 B

    hipMemsetAsync(loss, 0, 8, stream);
    k_prep_z<<<256, 256, 0, stream>>>(z, z16, zzp);
    k_prep_e<<<2048, 256, 0, stream>>>(emb, e16);
    k_gemm<<<2048, 512, 0, stream>>>(z16, e16, gmax16);
    k_rescore<<<4096, 256, 0, stream>>>(z, emb, zzp, gmax16, best);
    k_out<<<256, 256, 0, stream>>>(z, emb, best, out0, out2, loss);
    k_loss<<<1, 1, 0, stream>>>(loss, out1);
}